// Round 3
// baseline (449.526 us; speedup 1.0000x reference)
//
#include <hip/hip_runtime.h>
#include <cstdint>
#include <cstddef>

// Problem constants
#define B_N 65536
#define D_N 256
#define W_N 1024

typedef __bf16 bf16x8 __attribute__((ext_vector_type(8)));
typedef float f32x4 __attribute__((ext_vector_type(4)));
typedef unsigned short u16x8 __attribute__((ext_vector_type(8)));

__device__ __forceinline__ unsigned short f2bf(float f) {
  // round-to-nearest-even f32 -> bf16 (no NaN in this problem)
  unsigned u = __float_as_uint(f);
  u += 0x7fffu + ((u >> 16) & 1u);
  return (unsigned short)(u >> 16);
}

// ---------------------------------------------------------------------------
// Prep: cast W1 [1024x256] and W2 [256x1024] to bf16; M[j] = sum_i W1[j,i]*W2[i,j]
// ---------------------------------------------------------------------------
__global__ __launch_bounds__(256) void prep_kernel(
    const float* __restrict__ W1, const float* __restrict__ W2,
    unsigned short* __restrict__ W1b, unsigned short* __restrict__ W2b,
    float* __restrict__ M) {
  const int j = blockIdx.x;    // 0..1023
  const int t = threadIdx.x;   // 0..255
  const int gid = j * 256 + t; // covers 262144 exactly
  float w1 = W1[gid];
  float w2g = W2[gid];
  W1b[gid] = f2bf(w1);
  W2b[gid] = f2bf(w2g);
  float p = w1 * W2[t * W_N + j];
  #pragma unroll
  for (int m = 32; m; m >>= 1) p += __shfl_xor(p, m);
  __shared__ float red[4];
  if ((t & 63) == 0) red[t >> 6] = p;
  __syncthreads();
  if (t == 0) M[j] = red[0] + red[1] + red[2] + red[3];
}

// ---------------------------------------------------------------------------
// Split kernel A: pre = z @ W1^T + b1; h = softplus(pre) -> global Hb in
// blocked MFMA-A-fragment layout; trace = sigmoid(pre) @ M -> atomicAdd.
// 64 rows/block, 4 waves, wave owns 64 j-cols per 256-chunk. No barriers
// after z staging (no inter-wave exchange). One 64-AGPR accumulator only
// -> 3 waves/SIMD.
//
// Hb blocked layout (64-row block blk, bf16 element index):
//   blk*65536 + ((ksg*4 + a)*64 + qj*16 + l)*8 + e
//   where row = blk*64 + a*16 + l, j = ksg*32 + qj*8 + e.
// This is exactly the 16x16x32 A-fragment order: kernel B's lane (q,l15)
// reads 16B contiguous at slot ((ks*4+tm)*64 + lane).
// ---------------------------------------------------------------------------
__global__ __launch_bounds__(256, 3) void flow_a(
    const float* __restrict__ z, const float* __restrict__ b1,
    const unsigned short* __restrict__ W1b, const float* __restrict__ M,
    unsigned short* __restrict__ Hb, float* __restrict__ tr) {
  __shared__ __align__(16) unsigned short z_sh[64 * 256]; // 32 KB only

  const int tid = threadIdx.x;
  const int wave = tid >> 6;
  const int lane = tid & 63;
  const int l15 = lane & 15;
  const int q = lane >> 4;
  const int row0 = blockIdx.x * 64;
  const size_t hbase = (size_t)blockIdx.x * (64 * W_N);

  // ---- stage z tile [64 x 256] f32 -> bf16 blocked layout ----
  #pragma unroll
  for (int it = 0; it < 8; ++it) {
    int id = it * 256 + tid;
    int m = id >> 5;
    int o = id & 31;
    const float* gp = z + (size_t)(row0 + m) * D_N + o * 8;
    f32x4 a = *(const f32x4*)gp;
    f32x4 b = *(const f32x4*)(gp + 4);
    u16x8 v;
    v[0] = f2bf(a[0]); v[1] = f2bf(a[1]); v[2] = f2bf(a[2]); v[3] = f2bf(a[3]);
    v[4] = f2bf(b[0]); v[5] = f2bf(b[1]); v[6] = f2bf(b[2]); v[7] = f2bf(b[3]);
    int slot = (((o >> 2) * 4 + (m >> 4)) * 64 + (o & 3) * 16 + (m & 15));
    *(u16x8*)(z_sh + slot * 8) = v;
  }
  __syncthreads();

  float trp[4][4];
  #pragma unroll
  for (int a = 0; a < 4; ++a)
    #pragma unroll
    for (int r = 0; r < 4; ++r) trp[a][r] = 0.f;

  #pragma unroll 1
  for (int c = 0; c < 4; ++c) {
    const int j0 = c * 256;

    f32x4 acc1[4][4];
    #pragma unroll
    for (int a = 0; a < 4; ++a)
      #pragma unroll
      for (int b = 0; b < 4; ++b)
        acc1[a][b] = (f32x4){0.f, 0.f, 0.f, 0.f};

    // preload epilogue constants (hide under GEMM)
    float b1c[4], Mc[4];
    #pragma unroll
    for (int tn = 0; tn < 4; ++tn) {
      int jg = j0 + wave * 64 + tn * 16 + l15;
      b1c[tn] = b1[jg];
      Mc[tn] = M[jg];
    }

    #pragma unroll
    for (int ks = 0; ks < 8; ++ks) {
      bf16x8 afr[4];
      #pragma unroll
      for (int tm = 0; tm < 4; ++tm)
        afr[tm] = *(const bf16x8*)(z_sh + ((ks * 4 + tm) * 64 + lane) * 8);
      bf16x8 bfr[4];
      #pragma unroll
      for (int tn = 0; tn < 4; ++tn)
        bfr[tn] = *(const bf16x8*)(W1b +
            (size_t)(j0 + wave * 64 + tn * 16 + l15) * D_N + ks * 32 + q * 8);
      #pragma unroll
      for (int tm = 0; tm < 4; ++tm)
        #pragma unroll
        for (int tn = 0; tn < 4; ++tn)
          acc1[tm][tn] = __builtin_amdgcn_mfma_f32_16x16x32_bf16(
              afr[tm], bfr[tn], acc1[tm][tn], 0, 0, 0);
    }

    // ---- epilogue: softplus -> Hb (blocked layout), sigmoid*M -> trace ----
    #pragma unroll
    for (int tn = 0; tn < 4; ++tn) {
      const float b1v = b1c[tn];
      const float Mv = Mc[tn];
      const int ksg = c * 8 + wave * 2 + (tn >> 1);
      const int colp = ((tn & 1) * 2 + (l15 >> 3)) * 16;
      const int e = l15 & 7;
      #pragma unroll
      for (int tm = 0; tm < 4; ++tm) {
        #pragma unroll
        for (int r = 0; r < 4; ++r) {
          float x = acc1[tm][tn][r] + b1v;
          float ex = __expf(-fabsf(x));
          float inv = __builtin_amdgcn_rcpf(1.0f + ex);
          float sig = (x >= 0.f) ? inv : (1.0f - inv);
          float sp = fmaxf(x, 0.f) + __logf(1.0f + ex);
          trp[tm][r] += sig * Mv;
          size_t idx = hbase +
              (size_t)(((ksg * 4 + tm) * 64 + colp + q * 4 + r)) * 8 + e;
          Hb[idx] = f2bf(sp);
        }
      }
    }
  }

  // ---- trace: reduce across the 16 lanes of each quad, atomicAdd -sum ----
  #pragma unroll
  for (int tm = 0; tm < 4; ++tm) {
    #pragma unroll
    for (int r = 0; r < 4; ++r) {
      float v = trp[tm][r];
      v += __shfl_xor(v, 1);
      v += __shfl_xor(v, 2);
      v += __shfl_xor(v, 4);
      v += __shfl_xor(v, 8);
      if (l15 == 0) atomicAdd(tr + row0 + tm * 16 + q * 4 + r, -v);
    }
  }
}

// ---------------------------------------------------------------------------
// Split kernel B: dz = h @ W2^T. Pure GEMM, M=64 rows/block, N=256 (wave owns
// 64 i-cols), K=1024. Zero LDS, zero barriers. A-frags read 1KB-contiguous
// per wave from blocked Hb; B-frags from W2b (L2-resident). One 64-AGPR acc.
// K accumulation order (ks=0..31) identical to the fused kernel's (c,ks) order.
// ---------------------------------------------------------------------------
__global__ __launch_bounds__(256, 3) void flow_b(
    const unsigned short* __restrict__ Hb, const unsigned short* __restrict__ W2b,
    float* __restrict__ dz) {
  const int tid = threadIdx.x;
  const int wave = tid >> 6;
  const int lane = tid & 63;
  const int l15 = lane & 15;
  const int q = lane >> 4;
  const int row0 = blockIdx.x * 64;
  const unsigned short* hb = Hb + (size_t)blockIdx.x * (64 * W_N);

  f32x4 acc2[4][4];
  #pragma unroll
  for (int a = 0; a < 4; ++a)
    #pragma unroll
    for (int b = 0; b < 4; ++b)
      acc2[a][b] = (f32x4){0.f, 0.f, 0.f, 0.f};

  #pragma unroll 4
  for (int ks = 0; ks < 32; ++ks) {
    bf16x8 afr[4];
    #pragma unroll
    for (int tm = 0; tm < 4; ++tm)
      afr[tm] = *(const bf16x8*)(hb + ((ks * 4 + tm) * 64 + lane) * 8);
    bf16x8 bfr[4];
    #pragma unroll
    for (int tn = 0; tn < 4; ++tn)
      bfr[tn] = *(const bf16x8*)(W2b +
          (size_t)(wave * 64 + tn * 16 + l15) * W_N + ks * 32 + q * 8);
    #pragma unroll
    for (int tm = 0; tm < 4; ++tm)
      #pragma unroll
      for (int tn = 0; tn < 4; ++tn)
        acc2[tm][tn] = __builtin_amdgcn_mfma_f32_16x16x32_bf16(
            afr[tm], bfr[tn], acc2[tm][tn], 0, 0, 0);
  }

  #pragma unroll
  for (int tm = 0; tm < 4; ++tm)
    #pragma unroll
    for (int tn = 0; tn < 4; ++tn)
      #pragma unroll
      for (int r = 0; r < 4; ++r)
        dz[(size_t)(row0 + tm * 16 + q * 4 + r) * D_N + wave * 64 + tn * 16 + l15] =
            acc2[tm][tn][r];
}

// ---------------------------------------------------------------------------
// Fallback fused kernel (round-2 version) in case workspace is too small for Hb.
// ---------------------------------------------------------------------------
__device__ __forceinline__ void lds_barrier() {
  __builtin_amdgcn_sched_barrier(0);
  asm volatile("s_waitcnt lgkmcnt(0)" ::: "memory");
  __builtin_amdgcn_s_barrier();
  __builtin_amdgcn_sched_barrier(0);
}

__global__ __launch_bounds__(256, 2) void flow_kernel(
    const float* __restrict__ z, const float* __restrict__ b1,
    const unsigned short* __restrict__ W1b, const unsigned short* __restrict__ W2b,
    const float* __restrict__ M, float* __restrict__ dz, float* __restrict__ tr) {
  __shared__ __align__(16) unsigned short z_sh[64 * 256];
  __shared__ __align__(16) unsigned short h_sh[64 * 256];

  const int tid = threadIdx.x;
  const int wave = tid >> 6;
  const int lane = tid & 63;
  const int l15 = lane & 15;
  const int q = lane >> 4;
  const int row0 = blockIdx.x * 64;

  #pragma unroll
  for (int it = 0; it < 8; ++it) {
    int id = it * 256 + tid;
    int m = id >> 5;
    int o = id & 31;
    const float* gp = z + (size_t)(row0 + m) * D_N + o * 8;
    f32x4 a = *(const f32x4*)gp;
    f32x4 b = *(const f32x4*)(gp + 4);
    u16x8 v;
    v[0] = f2bf(a[0]); v[1] = f2bf(a[1]); v[2] = f2bf(a[2]); v[3] = f2bf(a[3]);
    v[4] = f2bf(b[0]); v[5] = f2bf(b[1]); v[6] = f2bf(b[2]); v[7] = f2bf(b[3]);
    int slot = (((o >> 2) * 4 + (m >> 4)) * 64 + (o & 3) * 16 + (m & 15));
    *(u16x8*)(z_sh + slot * 8) = v;
  }
  __syncthreads();

  f32x4 acc2[4][4];
  #pragma unroll
  for (int a = 0; a < 4; ++a)
    #pragma unroll
    for (int b = 0; b < 4; ++b)
      acc2[a][b] = (f32x4){0.f, 0.f, 0.f, 0.f};
  float trp[4][4];
  #pragma unroll
  for (int a = 0; a < 4; ++a)
    #pragma unroll
    for (int r = 0; r < 4; ++r) trp[a][r] = 0.f;

  #pragma unroll 1
  for (int c = 0; c < 4; ++c) {
    const int j0 = c * 256;
    const unsigned short* w1p[4];
    #pragma unroll
    for (int tn = 0; tn < 4; ++tn)
      w1p[tn] = W1b + (size_t)(j0 + wave * 64 + tn * 16 + l15) * D_N + q * 8;

    bf16x8 bq[3][4];
    #pragma unroll
    for (int p = 0; p < 3; ++p)
      #pragma unroll
      for (int tn = 0; tn < 4; ++tn)
        bq[p][tn] = *(const bf16x8*)(w1p[tn] + p * 32);

    float b1c[4], Mc[4];
    #pragma unroll
    for (int tn = 0; tn < 4; ++tn) {
      int jg = j0 + wave * 64 + tn * 16 + l15;
      b1c[tn] = b1[jg];
      Mc[tn] = M[jg];
    }

    f32x4 acc1[4][4];
    #pragma unroll
    for (int a = 0; a < 4; ++a)
      #pragma unroll
      for (int b = 0; b < 4; ++b)
        acc1[a][b] = (f32x4){0.f, 0.f, 0.f, 0.f};

    #pragma unroll
    for (int ks = 0; ks < 8; ++ks) {
      bf16x8 afr[4];
      #pragma unroll
      for (int tm = 0; tm < 4; ++tm)
        afr[tm] = *(const bf16x8*)(z_sh + ((ks * 4 + tm) * 64 + lane) * 8);
      #pragma unroll
      for (int tm = 0; tm < 4; ++tm)
        #pragma unroll
        for (int tn = 0; tn < 4; ++tn)
          acc1[tm][tn] = __builtin_amdgcn_mfma_f32_16x16x32_bf16(
              afr[tm], bq[ks % 3][tn], acc1[tm][tn], 0, 0, 0);
      if (ks < 5) {
        #pragma unroll
        for (int tn = 0; tn < 4; ++tn)
          bq[ks % 3][tn] = *(const bf16x8*)(w1p[tn] + (ks + 3) * 32);
      }
    }

    const unsigned short* w2p[4];
    #pragma unroll
    for (int tn = 0; tn < 4; ++tn)
      w2p[tn] = W2b + (size_t)(wave * 64 + tn * 16 + l15) * W_N + j0 + q * 8;
    bf16x8 cq[3][4];
    #pragma unroll
    for (int p = 0; p < 3; ++p)
      #pragma unroll
      for (int tn = 0; tn < 4; ++tn)
        cq[p][tn] = *(const bf16x8*)(w2p[tn] + p * 32);

    lds_barrier();

    #pragma unroll
    for (int tn = 0; tn < 4; ++tn) {
      const int jl = wave * 64 + tn * 16 + l15;
      const float b1v = b1c[tn];
      const float Mv = Mc[tn];
      const int slot_base = ((jl >> 5) * 4) * 64 + ((jl >> 3) & 3) * 16;
      const int byte_lo = (jl & 7);
      #pragma unroll
      for (int tm = 0; tm < 4; ++tm) {
        #pragma unroll
        for (int r = 0; r < 4; ++r) {
          float x = acc1[tm][tn][r] + b1v;
          float ex = __expf(-fabsf(x));
          float inv = __builtin_amdgcn_rcpf(1.0f + ex);
          float sig = (x >= 0.f) ? inv : (1.0f - inv);
          float sp = fmaxf(x, 0.f) + __logf(1.0f + ex);
          trp[tm][r] += sig * Mv;
          int slot = slot_base + tm * 64 + (q * 4 + r);
          h_sh[slot * 8 + byte_lo] = f2bf(sp);
        }
      }
    }

    lds_barrier();

    #pragma unroll
    for (int ks = 0; ks < 8; ++ks) {
      bf16x8 afr[4];
      #pragma unroll
      for (int tm = 0; tm < 4; ++tm)
        afr[tm] = *(const bf16x8*)(h_sh + ((ks * 4 + tm) * 64 + lane) * 8);
      #pragma unroll
      for (int tm = 0; tm < 4; ++tm)
        #pragma unroll
        for (int tn = 0; tn < 4; ++tn)
          acc2[tm][tn] = __builtin_amdgcn_mfma_f32_16x16x32_bf16(
              afr[tm], cq[ks % 3][tn], acc2[tm][tn], 0, 0, 0);
      if (ks < 5) {
        #pragma unroll
        for (int tn = 0; tn < 4; ++tn)
          cq[ks % 3][tn] = *(const bf16x8*)(w2p[tn] + (ks + 3) * 32);
      }
    }
  }

  #pragma unroll
  for (int tm = 0; tm < 4; ++tm)
    #pragma unroll
    for (int tn = 0; tn < 4; ++tn)
      #pragma unroll
      for (int r = 0; r < 4; ++r)
        dz[(size_t)(row0 + tm * 16 + q * 4 + r) * D_N + wave * 64 + tn * 16 + l15] =
            acc2[tm][tn][r];

  #pragma unroll
  for (int tm = 0; tm < 4; ++tm) {
    #pragma unroll
    for (int r = 0; r < 4; ++r) {
      float v = trp[tm][r];
      v += __shfl_xor(v, 1);
      v += __shfl_xor(v, 2);
      v += __shfl_xor(v, 4);
      v += __shfl_xor(v, 8);
      if (l15 == 0) atomicAdd(tr + row0 + tm * 16 + q * 4 + r, -v);
    }
  }
}

extern "C" void kernel_launch(void* const* d_in, const int* in_sizes, int n_in,
                              void* d_out, int out_size, void* d_ws, size_t ws_size,
                              hipStream_t stream) {
  (void)in_sizes; (void)n_in; (void)out_size;
  const float* z  = (const float*)d_in[1];
  const float* W1 = (const float*)d_in[2];
  const float* b1 = (const float*)d_in[3];
  const float* W2 = (const float*)d_in[4];
  float* dz = (float*)d_out;                    // [B, D]
  float* tr = dz + (size_t)B_N * D_N;           // [B]

  unsigned short* W1b = (unsigned short*)d_ws;   // 512 KB
  unsigned short* W2b = W1b + (size_t)W_N * D_N; // 512 KB
  float* M = (float*)(W2b + (size_t)W_N * D_N);  // 4 KB
  unsigned short* Hb = (unsigned short*)(M + W_N); // 134.2 MB (blocked h)

  const size_t need = (size_t)2 * W_N * D_N * 2 + (size_t)W_N * 4 +
                      (size_t)B_N * W_N * 2;

  hipMemsetAsync(tr, 0, B_N * sizeof(float), stream);
  prep_kernel<<<dim3(W_N), dim3(256), 0, stream>>>(W1, W2, W1b, W2b, M);
  if (ws_size >= need) {
    flow_a<<<dim3(B_N / 64), dim3(256), 0, stream>>>(z, b1, W1b, M, Hb, tr);
    flow_b<<<dim3(B_N / 64), dim3(256), 0, stream>>>(Hb, W2b, dz);
  } else {
    flow_kernel<<<dim3(B_N / 64), dim3(256), 0, stream>>>(z, b1, W1b, W2b, M, dz, tr);
  }
}

// Round 4
// 376.906 us; speedup vs baseline: 1.1927x; 1.1927x over previous
//
#include <hip/hip_runtime.h>
#include <cstdint>
#include <cstddef>

// Problem constants
#define B_N 65536
#define D_N 256
#define W_N 1024

typedef __bf16 bf16x8 __attribute__((ext_vector_type(8)));
typedef float f32x4 __attribute__((ext_vector_type(4)));
typedef unsigned short u16x8 __attribute__((ext_vector_type(8)));

__device__ __forceinline__ unsigned short f2bf(float f) {
  // round-to-nearest-even f32 -> bf16 (no NaN in this problem)
  unsigned u = __float_as_uint(f);
  u += 0x7fffu + ((u >> 16) & 1u);
  return (unsigned short)(u >> 16);
}

// Raw barrier that does NOT drain vmcnt (keeps global loads in flight).
// LDS hazards covered by lgkmcnt(0); sched_barrier(0) stops hoisting.
__device__ __forceinline__ void lds_barrier() {
  __builtin_amdgcn_sched_barrier(0);
  asm volatile("s_waitcnt lgkmcnt(0)" ::: "memory");
  __builtin_amdgcn_s_barrier();
  __builtin_amdgcn_sched_barrier(0);
}

// ---------------------------------------------------------------------------
// Prep: cast W1 [1024x256] and W2 [256x1024] to bf16; M[j] = sum_i W1[j,i]*W2[i,j]
// ---------------------------------------------------------------------------
__global__ __launch_bounds__(256) void prep_kernel(
    const float* __restrict__ W1, const float* __restrict__ W2,
    unsigned short* __restrict__ W1b, unsigned short* __restrict__ W2b,
    float* __restrict__ M) {
  const int j = blockIdx.x;    // 0..1023
  const int t = threadIdx.x;   // 0..255
  const int gid = j * 256 + t; // covers 262144 exactly
  float w1 = W1[gid];
  float w2g = W2[gid];
  W1b[gid] = f2bf(w1);
  W2b[gid] = f2bf(w2g);
  float p = w1 * W2[t * W_N + j];
  #pragma unroll
  for (int m = 32; m; m >>= 1) p += __shfl_xor(p, m);
  __shared__ float red[4];
  if ((t & 63) == 0) red[t >> 6] = p;
  __syncthreads();
  if (t == 0) M[j] = red[0] + red[1] + red[2] + red[3];
}

// ---------------------------------------------------------------------------
// Fused flow kernel, BM = 32 rows/block (grid 2048), 4 waves.
// Rationale (round-3 evidence): occupancy is register-capped. BM=32 halves
// both MFMA accumulators (acc1+acc2 = 64 regs vs 128), fitting 3 waves/SIMD
// (__launch_bounds__(256,3)) with 32 KB LDS -> 3 blocks/CU, 12 waves/CU.
//
// LDS blocked layout for a [32 x 256] bf16 tile (z and h):
//   element (m,k) -> 16B slot ((k/32)*2 + m/16)*64 + ((k%32)/8)*16 + (m%16),
//   elem-in-slot = k%8.  A-frag for (ks,tm): lane reads 16B at slot
//   ((ks*2+tm)*64 + lane).
// MFMA 16x16x32 bf16: A[m=lane&15][k=(lane>>4)*8+j]; C row=(lane>>4)*4+reg,
// col=lane&15.
// ---------------------------------------------------------------------------
__global__ __launch_bounds__(256, 3) void flow_kernel(
    const float* __restrict__ z, const float* __restrict__ b1,
    const unsigned short* __restrict__ W1b, const unsigned short* __restrict__ W2b,
    const float* __restrict__ M, float* __restrict__ dz, float* __restrict__ tr) {
  __shared__ __align__(16) unsigned short z_sh[32 * 256]; // 16 KB
  __shared__ __align__(16) unsigned short h_sh[32 * 256]; // 16 KB

  const int tid = threadIdx.x;
  const int wave = tid >> 6;
  const int lane = tid & 63;
  const int l15 = lane & 15;
  const int q = lane >> 4; // quad 0..3
  const int row0 = blockIdx.x * 32;

  // ---- stage z tile [32 x 256] f32 -> bf16 blocked layout ----
  #pragma unroll
  for (int it = 0; it < 4; ++it) {
    int id = it * 256 + tid; // 0..1023 octets
    int m = id >> 5;  // row 0..31
    int o = id & 31;  // octet of 8 floats
    const float* gp = z + (size_t)(row0 + m) * D_N + o * 8;
    f32x4 a = *(const f32x4*)gp;
    f32x4 b = *(const f32x4*)(gp + 4);
    u16x8 v;
    v[0] = f2bf(a[0]); v[1] = f2bf(a[1]); v[2] = f2bf(a[2]); v[3] = f2bf(a[3]);
    v[4] = f2bf(b[0]); v[5] = f2bf(b[1]); v[6] = f2bf(b[2]); v[7] = f2bf(b[3]);
    int slot = (((o >> 2) * 2 + (m >> 4)) * 64 + (o & 3) * 16 + (m & 15));
    *(u16x8*)(z_sh + slot * 8) = v;
  }
  __syncthreads();

  f32x4 acc2[2][4]; // dz accumulator: rows tm*16+q*4+r, cols wave*64+tn*16+l15
  #pragma unroll
  for (int a = 0; a < 2; ++a)
    #pragma unroll
    for (int b = 0; b < 4; ++b)
      acc2[a][b] = (f32x4){0.f, 0.f, 0.f, 0.f};
  float trp[2][4]; // trace partial per (tm, reg)
  #pragma unroll
  for (int a = 0; a < 2; ++a)
    #pragma unroll
    for (int r = 0; r < 4; ++r) trp[a][r] = 0.f;

  #pragma unroll 1
  for (int c = 0; c < 4; ++c) {
    const int j0 = c * 256;

    f32x4 acc1[2][4];
    #pragma unroll
    for (int a = 0; a < 2; ++a)
      #pragma unroll
      for (int b = 0; b < 4; ++b)
        acc1[a][b] = (f32x4){0.f, 0.f, 0.f, 0.f};

    // preload epilogue constants (hide under GEMM1)
    float b1c[4], Mc[4];
    #pragma unroll
    for (int tn = 0; tn < 4; ++tn) {
      int jg = j0 + wave * 64 + tn * 16 + l15;
      b1c[tn] = b1[jg];
      Mc[tn] = M[jg];
    }

    // ---- GEMM1: pre[32 x 256chunk] = z_tile @ W1[j0+..]^T, K = 256 ----
    #pragma unroll
    for (int ks = 0; ks < 8; ++ks) {
      bf16x8 afr[2];
      #pragma unroll
      for (int tm = 0; tm < 2; ++tm)
        afr[tm] = *(const bf16x8*)(z_sh + ((ks * 2 + tm) * 64 + lane) * 8);
      bf16x8 bfr[4];
      #pragma unroll
      for (int tn = 0; tn < 4; ++tn)
        bfr[tn] = *(const bf16x8*)(W1b +
            (size_t)(j0 + wave * 64 + tn * 16 + l15) * D_N + ks * 32 + q * 8);
      #pragma unroll
      for (int tm = 0; tm < 2; ++tm)
        #pragma unroll
        for (int tn = 0; tn < 4; ++tn)
          acc1[tm][tn] = __builtin_amdgcn_mfma_f32_16x16x32_bf16(
              afr[tm], bfr[tn], acc1[tm][tn], 0, 0, 0);
    }

    lds_barrier(); // all waves done reading h_sh from previous chunk's GEMM2

    // ---- epilogue: softplus -> h_sh (blocked layout), sigmoid*M -> trace ----
    #pragma unroll
    for (int tn = 0; tn < 4; ++tn) {
      const int jl = wave * 64 + tn * 16 + l15; // chunk-local j, 0..255
      const float b1v = b1c[tn];
      const float Mv = Mc[tn];
      const int slot_base = (jl >> 5) * 128 + ((jl >> 3) & 3) * 16;
      const int elem_lo = jl & 7;
      #pragma unroll
      for (int tm = 0; tm < 2; ++tm) {
        #pragma unroll
        for (int r = 0; r < 4; ++r) {
          float x = acc1[tm][tn][r] + b1v;
          float ex = __expf(-fabsf(x));
          float inv = __builtin_amdgcn_rcpf(1.0f + ex);
          float sig = (x >= 0.f) ? inv : (1.0f - inv);
          float sp = fmaxf(x, 0.f) + __logf(1.0f + ex);
          trp[tm][r] += sig * Mv;
          int slot = slot_base + tm * 64 + (q * 4 + r); // row = tm*16 + q*4 + r
          h_sh[slot * 8 + elem_lo] = f2bf(sp);
        }
      }
    }

    lds_barrier(); // h_sh ready

    // ---- GEMM2: dz += h_chunk[32 x 256] @ W2[:, j0+..]^T, K = 256 ----
    #pragma unroll
    for (int ks = 0; ks < 8; ++ks) {
      bf16x8 afr[2];
      #pragma unroll
      for (int tm = 0; tm < 2; ++tm)
        afr[tm] = *(const bf16x8*)(h_sh + ((ks * 2 + tm) * 64 + lane) * 8);
      bf16x8 bfr[4];
      #pragma unroll
      for (int tn = 0; tn < 4; ++tn)
        bfr[tn] = *(const bf16x8*)(W2b +
            (size_t)(wave * 64 + tn * 16 + l15) * W_N + j0 + ks * 32 + q * 8);
      #pragma unroll
      for (int tm = 0; tm < 2; ++tm)
        #pragma unroll
        for (int tn = 0; tn < 4; ++tn)
          acc2[tm][tn] = __builtin_amdgcn_mfma_f32_16x16x32_bf16(
              afr[tm], bfr[tn], acc2[tm][tn], 0, 0, 0);
    }
  }

  // ---- store dz ----
  #pragma unroll
  for (int tm = 0; tm < 2; ++tm)
    #pragma unroll
    for (int tn = 0; tn < 4; ++tn)
      #pragma unroll
      for (int r = 0; r < 4; ++r)
        dz[(size_t)(row0 + tm * 16 + q * 4 + r) * D_N + wave * 64 + tn * 16 + l15] =
            acc2[tm][tn][r];

  // ---- trace: reduce across the 16 lanes of each quad, atomicAdd -sum ----
  #pragma unroll
  for (int tm = 0; tm < 2; ++tm) {
    #pragma unroll
    for (int r = 0; r < 4; ++r) {
      float v = trp[tm][r];
      v += __shfl_xor(v, 1);
      v += __shfl_xor(v, 2);
      v += __shfl_xor(v, 4);
      v += __shfl_xor(v, 8);
      if (l15 == 0) atomicAdd(tr + row0 + tm * 16 + q * 4 + r, -v);
    }
  }
}

extern "C" void kernel_launch(void* const* d_in, const int* in_sizes, int n_in,
                              void* d_out, int out_size, void* d_ws, size_t ws_size,
                              hipStream_t stream) {
  (void)in_sizes; (void)n_in; (void)out_size; (void)ws_size;
  // inputs: t[1], z[B,D], W1[W,D], b1[W], W2[D,W]  (all f32)
  const float* z  = (const float*)d_in[1];
  const float* W1 = (const float*)d_in[2];
  const float* b1 = (const float*)d_in[3];
  const float* W2 = (const float*)d_in[4];
  float* dz = (float*)d_out;                    // [B, D]
  float* tr = dz + (size_t)B_N * D_N;           // [B] = dlogpz_dt (negated trace)

  unsigned short* W1b = (unsigned short*)d_ws;   // 512 KB
  unsigned short* W2b = W1b + (size_t)W_N * D_N; // 512 KB
  float* M = (float*)(W2b + (size_t)W_N * D_N);  // 4 KB

  hipMemsetAsync(tr, 0, B_N * sizeof(float), stream);
  prep_kernel<<<dim3(W_N), dim3(256), 0, stream>>>(W1, W2, W1b, W2b, M);
  flow_kernel<<<dim3(B_N / 32), dim3(256), 0, stream>>>(z, b1, W1b, W2b, M, dz, tr);
}

// Round 6
// 290.607 us; speedup vs baseline: 1.5469x; 1.2970x over previous
//
#include <hip/hip_runtime.h>
#include <cstdint>
#include <cstddef>

// Problem constants
#define B_N 65536
#define D_N 256
#define W_N 1024

typedef __bf16 bf16x8 __attribute__((ext_vector_type(8)));
typedef float f32x4 __attribute__((ext_vector_type(4)));
typedef unsigned short u16x8 __attribute__((ext_vector_type(8)));

__device__ __forceinline__ unsigned short f2bf(float f) {
  // round-to-nearest-even f32 -> bf16 (no NaN in this problem)
  unsigned u = __float_as_uint(f);
  u += 0x7fffu + ((u >> 16) & 1u);
  return (unsigned short)(u >> 16);
}

// Raw barrier that does NOT drain vmcnt (keeps global loads in flight).
// LDS hazards covered by lgkmcnt(0); sched_barrier(0) stops hoisting.
__device__ __forceinline__ void lds_barrier() {
  __builtin_amdgcn_sched_barrier(0);
  asm volatile("s_waitcnt lgkmcnt(0)" ::: "memory");
  __builtin_amdgcn_s_barrier();
  __builtin_amdgcn_sched_barrier(0);
}

// ---------------------------------------------------------------------------
// Prep: cast W1 [1024x256] and W2 [256x1024] to bf16; M[j] = sum_i W1[j,i]*W2[i,j]
// ---------------------------------------------------------------------------
__global__ __launch_bounds__(256) void prep_kernel(
    const float* __restrict__ W1, const float* __restrict__ W2,
    unsigned short* __restrict__ W1b, unsigned short* __restrict__ W2b,
    float* __restrict__ M) {
  const int j = blockIdx.x;    // 0..1023
  const int t = threadIdx.x;   // 0..255
  const int gid = j * 256 + t; // covers 262144 exactly
  float w1 = W1[gid];
  float w2g = W2[gid];
  W1b[gid] = f2bf(w1);
  W2b[gid] = f2bf(w2g);
  float p = w1 * W2[t * W_N + j];
  #pragma unroll
  for (int m = 32; m; m >>= 1) p += __shfl_xor(p, m);
  __shared__ float red[4];
  if ((t & 63) == 0) red[t >> 6] = p;
  __syncthreads();
  if (t == 0) M[j] = red[0] + red[1] + red[2] + red[3];
}

// ---------------------------------------------------------------------------
// Fused flow kernel, BM = 128 rows/block, 512 threads = 8 waves (2 row-waves
// x 4 col-waves). Rationale (rounds 2-4 evidence): every config pins at
// ~6.5 TB/s of vmem load traffic; weight traffic = (B/BM) * 1 MB dominates.
// BM=128 halves it vs round 2 while keeping the per-wave register footprint
// (acc1 64 + acc2 64) that is proven to fit 2 waves/SIMD without spill.
//
// LDS: z and h as TWO 64-row sub-tiles, each in the blocked fragment layout:
//   element (ml,k) -> 16B slot ((k/32)*4 + ml/16)*64 + ((k%32)/8)*16 + (ml%16),
//   elem-in-slot = k%8; sub-tile s at offset s*16384 elems.
// A-frag for (ks,tm): lane reads 16B at sub-tile wm, slot ((ks*4+tm)*64+lane).
// MFMA 16x16x32 bf16: C row=(lane>>4)*4+reg, col=lane&15.
// ---------------------------------------------------------------------------
__global__ __launch_bounds__(512, 2) void flow_kernel(
    const float* __restrict__ z, const float* __restrict__ b1,
    const unsigned short* __restrict__ W1b, const unsigned short* __restrict__ W2b,
    const float* __restrict__ M, float* __restrict__ dz, float* __restrict__ tr) {
  __shared__ __align__(16) unsigned short z_sh[2 * 64 * 256]; // 64 KB
  __shared__ __align__(16) unsigned short h_sh[2 * 64 * 256]; // 64 KB

  const int tid = threadIdx.x;
  const int wave = tid >> 6;   // 0..7
  const int wm = wave >> 2;    // row-wave: sub-tile 0/1 (rows wm*64..)
  const int wn = wave & 3;     // col-wave: 64 j-cols (GEMM1) / 64 i-cols (GEMM2)
  const int lane = tid & 63;
  const int l15 = lane & 15;
  const int q = lane >> 4;     // quad 0..3
  const int row0 = blockIdx.x * 128;

  // ---- stage z tile [128 x 256] f32 -> bf16 blocked layout ----
  #pragma unroll
  for (int it = 0; it < 8; ++it) {
    int id = it * 512 + tid;   // 0..4095 octets
    int m = id >> 5;           // row 0..127
    int o = id & 31;           // octet of 8 floats
    const float* gp = z + (size_t)(row0 + m) * D_N + o * 8;
    f32x4 a = *(const f32x4*)gp;
    f32x4 b = *(const f32x4*)(gp + 4);
    u16x8 v;
    v[0] = f2bf(a[0]); v[1] = f2bf(a[1]); v[2] = f2bf(a[2]); v[3] = f2bf(a[3]);
    v[4] = f2bf(b[0]); v[5] = f2bf(b[1]); v[6] = f2bf(b[2]); v[7] = f2bf(b[3]);
    int s = m >> 6;            // sub-tile
    int ml = m & 63;
    int slot = (((o >> 2) * 4 + (ml >> 4)) * 64 + (o & 3) * 16 + (ml & 15));
    *(u16x8*)(z_sh + s * 16384 + slot * 8) = v;
  }
  __syncthreads();

  f32x4 acc2[4][4]; // dz acc: rows row0+wm*64+tm*16+q*4+r, cols wn*64+tn*16+l15
  #pragma unroll
  for (int a = 0; a < 4; ++a)
    #pragma unroll
    for (int b = 0; b < 4; ++b)
      acc2[a][b] = (f32x4){0.f, 0.f, 0.f, 0.f};
  float trp[4][4]; // trace partial per (tm, reg)
  #pragma unroll
  for (int a = 0; a < 4; ++a)
    #pragma unroll
    for (int r = 0; r < 4; ++r) trp[a][r] = 0.f;

  #pragma unroll 1
  for (int c = 0; c < 4; ++c) {
    const int j0 = c * 256;

    // Per-tn W1 base pointers (ks walks via immediate offsets)
    const unsigned short* w1p[4];
    #pragma unroll
    for (int tn = 0; tn < 4; ++tn)
      w1p[tn] = W1b + (size_t)(j0 + wn * 64 + tn * 16 + l15) * D_N + q * 8;

    // ---- GEMM1 B pipeline: preissue ks = 0,1,2 into 3 register sets ----
    bf16x8 bq[3][4];
    #pragma unroll
    for (int p = 0; p < 3; ++p)
      #pragma unroll
      for (int tn = 0; tn < 4; ++tn)
        bq[p][tn] = *(const bf16x8*)(w1p[tn] + p * 32);

    // Preload epilogue constants under GEMM1 latency
    float b1c[4], Mc[4];
    #pragma unroll
    for (int tn = 0; tn < 4; ++tn) {
      int jg = j0 + wn * 64 + tn * 16 + l15;
      b1c[tn] = b1[jg];
      Mc[tn] = M[jg];
    }

    f32x4 acc1[4][4];
    #pragma unroll
    for (int a = 0; a < 4; ++a)
      #pragma unroll
      for (int b = 0; b < 4; ++b)
        acc1[a][b] = (f32x4){0.f, 0.f, 0.f, 0.f};

    // ---- GEMM1: pre[rows wm*64.. x cols j0+wn*64..] = z @ W1^T, K=256 ----
    #pragma unroll
    for (int ks = 0; ks < 8; ++ks) {
      bf16x8 afr[4];
      #pragma unroll
      for (int tm = 0; tm < 4; ++tm)
        afr[tm] = *(const bf16x8*)(z_sh + wm * 16384 +
                                   ((ks * 4 + tm) * 64 + lane) * 8);
      #pragma unroll
      for (int tm = 0; tm < 4; ++tm)
        #pragma unroll
        for (int tn = 0; tn < 4; ++tn)
          acc1[tm][tn] = __builtin_amdgcn_mfma_f32_16x16x32_bf16(
              afr[tm], bq[ks % 3][tn], acc1[tm][tn], 0, 0, 0);
      if (ks < 5) { // reload this set for step ks+3
        #pragma unroll
        for (int tn = 0; tn < 4; ++tn)
          bq[ks % 3][tn] = *(const bf16x8*)(w1p[tn] + (ks + 3) * 32);
      }
    }

    // ---- preissue GEMM2 B sets 0..2 (latency hides under epilogue) ----
    const unsigned short* w2p[4];
    #pragma unroll
    for (int tn = 0; tn < 4; ++tn)
      w2p[tn] = W2b + (size_t)(wn * 64 + tn * 16 + l15) * W_N + j0 + q * 8;
    bf16x8 cq[3][4];
    #pragma unroll
    for (int p = 0; p < 3; ++p)
      #pragma unroll
      for (int tn = 0; tn < 4; ++tn)
        cq[p][tn] = *(const bf16x8*)(w2p[tn] + p * 32);

    lds_barrier(); // all waves done reading h_sh from previous chunk's GEMM2

    // ---- epilogue: softplus -> h_sh (blocked, sub-tile wm), sigmoid*M -> tr
    #pragma unroll
    for (int tn = 0; tn < 4; ++tn) {
      const int jl = wn * 64 + tn * 16 + l15; // chunk-local j, 0..255
      const float b1v = b1c[tn];
      const float Mv = Mc[tn];
      const int slot_base = ((jl >> 5) * 4) * 64 + ((jl >> 3) & 3) * 16;
      const int elem_lo = jl & 7;
      #pragma unroll
      for (int tm = 0; tm < 4; ++tm) {
        #pragma unroll
        for (int r = 0; r < 4; ++r) {
          float x = acc1[tm][tn][r] + b1v;
          float ex = __expf(-fabsf(x));
          float inv = __builtin_amdgcn_rcpf(1.0f + ex);
          float sig = (x >= 0.f) ? inv : (1.0f - inv);
          float sp = fmaxf(x, 0.f) + __logf(1.0f + ex);
          trp[tm][r] += sig * Mv;
          int slot = slot_base + tm * 64 + (q * 4 + r); // row-in-sub = tm*16+q*4+r
          h_sh[wm * 16384 + slot * 8 + elem_lo] = f2bf(sp);
        }
      }
    }

    lds_barrier(); // h_sh ready

    // ---- GEMM2: dz += h[rows wm*64..] @ W2[cols wn*64..]^T, K=256 ----
    #pragma unroll
    for (int ks = 0; ks < 8; ++ks) {
      bf16x8 afr[4];
      #pragma unroll
      for (int tm = 0; tm < 4; ++tm)
        afr[tm] = *(const bf16x8*)(h_sh + wm * 16384 +
                                   ((ks * 4 + tm) * 64 + lane) * 8);
      #pragma unroll
      for (int tm = 0; tm < 4; ++tm)
        #pragma unroll
        for (int tn = 0; tn < 4; ++tn)
          acc2[tm][tn] = __builtin_amdgcn_mfma_f32_16x16x32_bf16(
              afr[tm], cq[ks % 3][tn], acc2[tm][tn], 0, 0, 0);
      if (ks < 5) { // reload this set for step ks+3
        #pragma unroll
        for (int tn = 0; tn < 4; ++tn)
          cq[ks % 3][tn] = *(const bf16x8*)(w2p[tn] + (ks + 3) * 32);
      }
    }
  }

  // ---- store dz ----
  #pragma unroll
  for (int tm = 0; tm < 4; ++tm)
    #pragma unroll
    for (int tn = 0; tn < 4; ++tn)
      #pragma unroll
      for (int r = 0; r < 4; ++r)
        dz[(size_t)(row0 + wm * 64 + tm * 16 + q * 4 + r) * D_N +
           wn * 64 + tn * 16 + l15] = acc2[tm][tn][r];

  // ---- trace: reduce across the 16 lanes of each quad, atomicAdd -sum ----
  #pragma unroll
  for (int tm = 0; tm < 4; ++tm) {
    #pragma unroll
    for (int r = 0; r < 4; ++r) {
      float v = trp[tm][r];
      v += __shfl_xor(v, 1);
      v += __shfl_xor(v, 2);
      v += __shfl_xor(v, 4);
      v += __shfl_xor(v, 8);
      if (l15 == 0)
        atomicAdd(tr + row0 + wm * 64 + tm * 16 + q * 4 + r, -v);
    }
  }
}

extern "C" void kernel_launch(void* const* d_in, const int* in_sizes, int n_in,
                              void* d_out, int out_size, void* d_ws, size_t ws_size,
                              hipStream_t stream) {
  (void)in_sizes; (void)n_in; (void)out_size; (void)ws_size;
  // inputs: t[1], z[B,D], W1[W,D], b1[W], W2[D,W]  (all f32)
  const float* z  = (const float*)d_in[1];
  const float* W1 = (const float*)d_in[2];
  const float* b1 = (const float*)d_in[3];
  const float* W2 = (const float*)d_in[4];
  float* dz = (float*)d_out;                    // [B, D]
  float* tr = dz + (size_t)B_N * D_N;           // [B] = dlogpz_dt (negated trace)

  unsigned short* W1b = (unsigned short*)d_ws;   // 512 KB
  unsigned short* W2b = W1b + (size_t)W_N * D_N; // 512 KB
  float* M = (float*)(W2b + (size_t)W_N * D_N);  // 4 KB

  hipMemsetAsync(tr, 0, B_N * sizeof(float), stream);
  prep_kernel<<<dim3(W_N), dim3(256), 0, stream>>>(W1, W2, W1b, W2b, M);
  flow_kernel<<<dim3(B_N / 128), dim3(512), 0, stream>>>(z, b1, W1b, W2b, M, dz, tr);
}

// Round 7
// 281.222 us; speedup vs baseline: 1.5985x; 1.0334x over previous
//
#include <hip/hip_runtime.h>
#include <cstdint>
#include <cstddef>

// Problem constants
#define B_N 65536
#define D_N 256
#define W_N 1024

typedef __bf16 bf16x8 __attribute__((ext_vector_type(8)));
typedef float f32x4 __attribute__((ext_vector_type(4)));
typedef unsigned short u16x8 __attribute__((ext_vector_type(8)));

__device__ __forceinline__ unsigned short f2bf(float f) {
  // round-to-nearest-even f32 -> bf16 (no NaN in this problem)
  unsigned u = __float_as_uint(f);
  u += 0x7fffu + ((u >> 16) & 1u);
  return (unsigned short)(u >> 16);
}

// Raw barrier that does NOT drain vmcnt (keeps global loads in flight).
// LDS hazards covered by lgkmcnt(0); sched_barrier(0) stops hoisting.
__device__ __forceinline__ void lds_barrier() {
  __builtin_amdgcn_sched_barrier(0);
  asm volatile("s_waitcnt lgkmcnt(0)" ::: "memory");
  __builtin_amdgcn_s_barrier();
  __builtin_amdgcn_sched_barrier(0);
}

// ---------------------------------------------------------------------------
// Prep: cast W1 [1024x256] and W2 [256x1024] to bf16; M[j] = sum_i W1[j,i]*W2[i,j]
// ---------------------------------------------------------------------------
__global__ __launch_bounds__(256) void prep_kernel(
    const float* __restrict__ W1, const float* __restrict__ W2,
    unsigned short* __restrict__ W1b, unsigned short* __restrict__ W2b,
    float* __restrict__ M) {
  const int j = blockIdx.x;    // 0..1023
  const int t = threadIdx.x;   // 0..255
  const int gid = j * 256 + t; // covers 262144 exactly
  float w1 = W1[gid];
  float w2g = W2[gid];
  W1b[gid] = f2bf(w1);
  W2b[gid] = f2bf(w2g);
  float p = w1 * W2[t * W_N + j];
  #pragma unroll
  for (int m = 32; m; m >>= 1) p += __shfl_xor(p, m);
  __shared__ float red[4];
  if ((t & 63) == 0) red[t >> 6] = p;
  __syncthreads();
  if (t == 0) M[j] = red[0] + red[1] + red[2] + red[3];
}

// ---------------------------------------------------------------------------
// Fused flow kernel, BM = 64 rows/block (grid 1024), 4 waves, chunk of 256 j
// processed as TWO 128-j halves.
// Rationale (rounds 2/4/6 evidence): the kernel is latency-bound with every
// pipe <40%; the binding constraints are registers (acc1+acc2=128 -> 2
// waves/SIMD) and LDS (64KB -> 2 blocks/CU), and barrier phase-locking.
// Halving the GEMM1 j-panel cuts acc1 to 32 regs and h_sh to 16KB:
//   LDS = 32KB(z) + 16KB(h) = 48KB  -> 3 blocks/CU
//   ~156 VGPR peak -> __launch_bounds__(256,3) -> 3 waves/SIMD, 12 waves/CU
// Co-resident blocks run desynchronized phases (epilogue VALU overlaps other
// blocks' MFMA). K-accumulation order of acc2 (ascending j in 32-steps) is
// identical to previous versions -> bitwise-identical dz.
//
// LDS blocked layout (z, [64 x 256]):
//   (m,k) -> 16B slot ((k/32)*4 + m/16)*64 + ((k%32)/8)*16 + (m%16), elem k%8.
//   A-frag (ks,tm): lane reads 16B at slot ((ks*4+tm)*64 + lane).
// h_sh half-buffer [64 rows x 128 j-local]: same formula with jl2 = j - half0:
//   slot ((jl2/32)*4 + m/16)*64 + ((jl2%32)/8)*16 + (m%16), elem jl2%8.
// MFMA 16x16x32 bf16: C row=(lane>>4)*4+reg, col=lane&15.
// ---------------------------------------------------------------------------
__global__ __launch_bounds__(256, 3) void flow_kernel(
    const float* __restrict__ z, const float* __restrict__ b1,
    const unsigned short* __restrict__ W1b, const unsigned short* __restrict__ W2b,
    const float* __restrict__ M, float* __restrict__ dz, float* __restrict__ tr) {
  __shared__ __align__(16) unsigned short z_sh[64 * 256]; // 32 KB
  __shared__ __align__(16) unsigned short h_sh[64 * 128]; // 16 KB (one half)

  const int tid = threadIdx.x;
  const int w = tid >> 6;      // wave 0..3
  const int lane = tid & 63;
  const int l15 = lane & 15;
  const int q = lane >> 4;     // quad 0..3
  const int row0 = blockIdx.x * 64;

  // ---- stage z tile [64 x 256] f32 -> bf16 blocked layout ----
  #pragma unroll
  for (int it = 0; it < 8; ++it) {
    int id = it * 256 + tid;
    int m = id >> 5;  // row 0..63
    int o = id & 31;  // octet of 8 floats
    const float* gp = z + (size_t)(row0 + m) * D_N + o * 8;
    f32x4 a = *(const f32x4*)gp;
    f32x4 b = *(const f32x4*)(gp + 4);
    u16x8 v;
    v[0] = f2bf(a[0]); v[1] = f2bf(a[1]); v[2] = f2bf(a[2]); v[3] = f2bf(a[3]);
    v[4] = f2bf(b[0]); v[5] = f2bf(b[1]); v[6] = f2bf(b[2]); v[7] = f2bf(b[3]);
    int slot = (((o >> 2) * 4 + (m >> 4)) * 64 + (o & 3) * 16 + (m & 15));
    *(u16x8*)(z_sh + slot * 8) = v;
  }
  __syncthreads();

  f32x4 acc2[4][4]; // dz acc: rows row0+tm*16+q*4+r, cols w*64+tn*16+l15
  #pragma unroll
  for (int a = 0; a < 4; ++a)
    #pragma unroll
    for (int b = 0; b < 4; ++b)
      acc2[a][b] = (f32x4){0.f, 0.f, 0.f, 0.f};
  float trp[4][4]; // trace partial per (tm, reg)
  #pragma unroll
  for (int a = 0; a < 4; ++a)
    #pragma unroll
    for (int r = 0; r < 4; ++r) trp[a][r] = 0.f;

  #pragma unroll 1
  for (int c = 0; c < 4; ++c) {
    #pragma unroll
    for (int p = 0; p < 2; ++p) {
      const int jb = c * 256 + p * 128; // 128-j half base

      // ---- GEMM1: pre[64 x 128half] = z_tile @ W1[jb..]^T, K = 256 ----
      f32x4 acc1[4][2];
      #pragma unroll
      for (int a = 0; a < 4; ++a)
        #pragma unroll
        for (int b = 0; b < 2; ++b)
          acc1[a][b] = (f32x4){0.f, 0.f, 0.f, 0.f};

      // preload epilogue constants (hide under GEMM1)
      float b1c[2], Mc[2];
      #pragma unroll
      for (int tn = 0; tn < 2; ++tn) {
        int jg = jb + w * 32 + tn * 16 + l15;
        b1c[tn] = b1[jg];
        Mc[tn] = M[jg];
      }

      #pragma unroll
      for (int ks = 0; ks < 8; ++ks) {
        bf16x8 afr[4];
        #pragma unroll
        for (int tm = 0; tm < 4; ++tm)
          afr[tm] = *(const bf16x8*)(z_sh + ((ks * 4 + tm) * 64 + lane) * 8);
        bf16x8 bfr[2];
        #pragma unroll
        for (int tn = 0; tn < 2; ++tn)
          bfr[tn] = *(const bf16x8*)(W1b +
              (size_t)(jb + w * 32 + tn * 16 + l15) * D_N + ks * 32 + q * 8);
        #pragma unroll
        for (int tm = 0; tm < 4; ++tm)
          #pragma unroll
          for (int tn = 0; tn < 2; ++tn)
            acc1[tm][tn] = __builtin_amdgcn_mfma_f32_16x16x32_bf16(
                afr[tm], bfr[tn], acc1[tm][tn], 0, 0, 0);
      }

      lds_barrier(); // all waves done reading h_sh from previous half's GEMM2

      // ---- epilogue: softplus -> h_sh (blocked), sigmoid*M -> trace ----
      #pragma unroll
      for (int tn = 0; tn < 2; ++tn) {
        // jl2 = w*32 + tn*16 + l15 (0..127)
        const float b1v = b1c[tn];
        const float Mv = Mc[tn];
        const int grp = ((tn * 16 + l15) >> 3) & 3; // (jl2%32)/8
        const int elem = l15 & 7;                   // jl2%8
        #pragma unroll
        for (int tm = 0; tm < 4; ++tm) {
          #pragma unroll
          for (int r = 0; r < 4; ++r) {
            float x = acc1[tm][tn][r] + b1v;
            float ex = __expf(-fabsf(x));
            float inv = __builtin_amdgcn_rcpf(1.0f + ex);
            float sig = (x >= 0.f) ? inv : (1.0f - inv);
            float sp = fmaxf(x, 0.f) + __logf(1.0f + ex);
            trp[tm][r] += sig * Mv;
            int slot = (w * 4 + tm) * 64 + grp * 16 + (q * 4 + r);
            h_sh[slot * 8 + elem] = f2bf(sp);
          }
        }
      }

      lds_barrier(); // h half ready

      // ---- GEMM2: dz += h_half[64 x 128] @ W2[:, jb..]^T, K = 128 ----
      #pragma unroll
      for (int ks = 0; ks < 4; ++ks) {
        bf16x8 afr[4];
        #pragma unroll
        for (int tm = 0; tm < 4; ++tm)
          afr[tm] = *(const bf16x8*)(h_sh + ((ks * 4 + tm) * 64 + lane) * 8);
        bf16x8 bfr[4];
        #pragma unroll
        for (int tn = 0; tn < 4; ++tn)
          bfr[tn] = *(const bf16x8*)(W2b +
              (size_t)(w * 64 + tn * 16 + l15) * W_N + jb + ks * 32 + q * 8);
        #pragma unroll
        for (int tm = 0; tm < 4; ++tm)
          #pragma unroll
          for (int tn = 0; tn < 4; ++tn)
            acc2[tm][tn] = __builtin_amdgcn_mfma_f32_16x16x32_bf16(
                afr[tm], bfr[tn], acc2[tm][tn], 0, 0, 0);
      }
    }
  }

  // ---- store dz ----
  #pragma unroll
  for (int tm = 0; tm < 4; ++tm)
    #pragma unroll
    for (int tn = 0; tn < 4; ++tn)
      #pragma unroll
      for (int r = 0; r < 4; ++r)
        dz[(size_t)(row0 + tm * 16 + q * 4 + r) * D_N + w * 64 + tn * 16 + l15] =
            acc2[tm][tn][r];

  // ---- trace: reduce across the 16 lanes of each quad, atomicAdd -sum ----
  #pragma unroll
  for (int tm = 0; tm < 4; ++tm) {
    #pragma unroll
    for (int r = 0; r < 4; ++r) {
      float v = trp[tm][r];
      v += __shfl_xor(v, 1);
      v += __shfl_xor(v, 2);
      v += __shfl_xor(v, 4);
      v += __shfl_xor(v, 8);
      if (l15 == 0) atomicAdd(tr + row0 + tm * 16 + q * 4 + r, -v);
    }
  }
}

extern "C" void kernel_launch(void* const* d_in, const int* in_sizes, int n_in,
                              void* d_out, int out_size, void* d_ws, size_t ws_size,
                              hipStream_t stream) {
  (void)in_sizes; (void)n_in; (void)out_size; (void)ws_size;
  // inputs: t[1], z[B,D], W1[W,D], b1[W], W2[D,W]  (all f32)
  const float* z  = (const float*)d_in[1];
  const float* W1 = (const float*)d_in[2];
  const float* b1 = (const float*)d_in[3];
  const float* W2 = (const float*)d_in[4];
  float* dz = (float*)d_out;                    // [B, D]
  float* tr = dz + (size_t)B_N * D_N;           // [B] = dlogpz_dt (negated trace)

  unsigned short* W1b = (unsigned short*)d_ws;   // 512 KB
  unsigned short* W2b = W1b + (size_t)W_N * D_N; // 512 KB
  float* M = (float*)(W2b + (size_t)W_N * D_N);  // 4 KB

  hipMemsetAsync(tr, 0, B_N * sizeof(float), stream);
  prep_kernel<<<dim3(W_N), dim3(256), 0, stream>>>(W1, W2, W1b, W2b, M);
  flow_kernel<<<dim3(B_N / 64), dim3(256), 0, stream>>>(z, b1, W1b, W2b, M, dz, tr);
}